// Round 6
// baseline (224.777 us; speedup 1.0000x reference)
//
#include <hip/hip_runtime.h>

#define HWSZ 65536        // H*W
#define KSEL 32768u       // int(0.5*H*W)
#define CCH  128          // channels
#define BN   4            // batch
#define NG   (CCH * BN)   // 512 groups; group g = b*CCH + c, contiguous HWSZ floats
#define BPG  4            // partial blocks per group
#define NB1  (NG * BPG)   // 2048 blocks = 8 blocks/CU * 256 CU, zero tail
#define ELB  (HWSZ / BPG) // 16384 elements per block
#define NT1  256
#define NW1  4            // waves per block (histogram replicas)
#define NBINS 1024        // uniform-in-h bins: balanced atomics, no log in stream
#define HMIN  1.0e-3
#define NT2  256
#define NSUP  64          // supers of 16 bins for galloping merge

// ---------------- Kernel 1: pure streaming count histogram over h (no log, no w) ----------------
__global__ void __launch_bounds__(NT1) hist_kernel(
    const float* __restrict__ hsi, unsigned* __restrict__ hist_ws) {
    __shared__ unsigned hist[NW1][NBINS];   // 16 KB -> 8 blocks/CU (thread-limited)
    const int blk = blockIdx.x;
    const int g   = blk >> 2;
    const int p   = blk & 3;
    const int tid = threadIdx.x;
    const float S  = (float)NBINS / (1.0f - (float)HMIN);  // h in [1e-3, 1)
    const float C0 = -(float)HMIN * S;

    for (int i = tid; i < NW1 * NBINS; i += NT1) (&hist[0][0])[i] = 0u;
    __syncthreads();

    const float4* __restrict__ src =
        (const float4*)(hsi + (size_t)g * HWSZ + (size_t)p * ELB);
    unsigned* myh = hist[tid >> 6];
    #pragma unroll 4
    for (int i = 0; i < ELB / 4 / NT1; ++i) {    // 16 coalesced float4 iters
        float4 v = src[i * NT1 + tid];
        #pragma unroll
        for (int j = 0; j < 4; ++j) {
            int ib = (int)fmaf((&v.x)[j], S, C0);       // bin on h directly
            ib = min(max(ib, 0), (int)NBINS - 1);       // fp-edge safety
            atomicAdd(&myh[ib], 1u);
        }
    }
    __syncthreads();

    unsigned* out = hist_ws + (size_t)blk * NBINS;
    for (int b = tid; b < NBINS; b += NT1)
        out[b] = hist[0][b] + hist[1][b] + hist[2][b] + hist[3][b];
}

// ---------------- Kernel 2: per group — merge partials; e(bin) is unimodal; ----------------
// top-k = contiguous interval around the peak, found by galloping two-pointer merge.
__global__ void __launch_bounds__(NT2) reduce_kernel(
    const unsigned* __restrict__ hist_ws, const float* __restrict__ wp,
    double* __restrict__ total_sum, double* __restrict__ topk_sum) {
    __shared__ unsigned cntS[NBINS];        // 4 KB
    __shared__ double   ecS[NBINS];         // 8 KB
    __shared__ unsigned thrCnt[NT2];
    __shared__ double   thrCE[NT2];
    __shared__ unsigned supCnt[NSUP];
    __shared__ double   supCE[NSUP];
    __shared__ double   redA[NT2 / 64];

    const int g   = blockIdx.x;
    const int tid = threadIdx.x;
    const double w    = (double)wp[0];
    const double binw = (1.0 - HMIN) / (double)NBINS;

    // merge BPG partial histograms (vectorized 16B loads; thread owns bins 4*tid..4*tid+3)
    const uint4* base = (const uint4*)(hist_ws + (size_t)g * BPG * NBINS);
    uint4 p0 = base[tid];
    uint4 p1 = base[NBINS / 4 + tid];
    uint4 p2 = base[2 * (NBINS / 4) + tid];
    uint4 p3 = base[3 * (NBINS / 4) + tid];
    unsigned c[4] = { p0.x + p1.x + p2.x + p3.x, p0.y + p1.y + p2.y + p3.y,
                      p0.z + p1.z + p2.z + p3.z, p0.w + p1.w + p2.w + p3.w };
    double ce = 0.0; unsigned cs = 0u;
    #pragma unroll
    for (int j = 0; j < 4; ++j) {
        int b = tid * 4 + j;
        double hc = HMIN + ((double)b + 0.5) * binw;   // bin-center h (uniform within bin -> 2nd-order accurate)
        double f1 = w * hc;
        double e  = -f1 * log(f1);
        cntS[b] = c[j]; ecS[b] = e;
        ce += (double)c[j] * e; cs += c[j];
    }
    thrCnt[tid] = cs; thrCE[tid] = ce;
    double pall = ce;
    #pragma unroll
    for (int off = 32; off > 0; off >>= 1) pall += __shfl_down(pall, off);
    if ((tid & 63) == 0) redA[tid >> 6] = pall;
    __syncthreads();
    if (tid < NSUP) {   // 16-bin super aggregates for galloping
        unsigned s = 0u; double se = 0.0;
        #pragma unroll
        for (int j = 0; j < 4; ++j) { s += thrCnt[tid * 4 + j]; se += thrCE[tid * 4 + j]; }
        supCnt[tid] = s; supCE[tid] = se;
    }
    __syncthreads();

    if (tid == 0) {
        total_sum[g] = redA[0] + redA[1] + redA[2] + redA[3];

        // peak bin: contains h* = 1/(e*w); e(bin) ascending left of it, descending right
        double hstar = 1.0 / (2.718281828459045 * w);
        int p = (int)floor((hstar - HMIN) / binw);
        p = min(max(p, 0), (int)NBINS - 1);

        // galloping two-pointer merge of the two descending branches
        int L = p, R = p + 1;
        unsigned cnt = 0u; double sum = 0.0; int tb = -1;
        while (true) {
            if (L >= 0 && (L & 15) == 15) {          // whole left super outranks right head?
                int s = L >> 4;
                if ((R > (int)NBINS - 1 || ecS[s * 16] >= ecS[R]) && cnt + supCnt[s] < KSEL) {
                    cnt += supCnt[s]; sum += supCE[s]; L -= 16; continue;
                }
            }
            if (R <= (int)NBINS - 1 && (R & 15) == 0) {  // whole right super outranks left head?
                int s = R >> 4;
                if ((L < 0 || ecS[s * 16 + 15] >= ecS[L]) && cnt + supCnt[s] < KSEL) {
                    cnt += supCnt[s]; sum += supCE[s]; R += 16; continue;
                }
            }
            bool useL = (L >= 0) && (R > (int)NBINS - 1 || ecS[L] >= ecS[R]);
            int bb = useL ? L : R;
            unsigned cb = cntS[bb];
            if (cnt + cb >= KSEL) { tb = bb; break; }    // boundary bin
            cnt += cb; sum += (double)cb * ecS[bb];
            if (useL) --L; else ++R;
        }
        topk_sum[g] = sum + (double)(KSEL - cnt) * ecS[tb];
    }
}

// ---------------- Final: channel deltas + stable top-3 indices ----------------
__global__ void final_kernel(const double* __restrict__ total_sum,
                             const double* __restrict__ topk_sum,
                             int* __restrict__ out) {
    __shared__ double delta[CCH];
    const int c = threadIdx.x;
    double th = 0.0, tot = 0.0;
    for (int b = 0; b < BN; ++b) {
        th  += topk_sum[b * CCH + c];
        tot += total_sum[b * CCH + c];
    }
    // ranking monotone in (mean_high - mean)
    delta[c] = th / ((double)BN * (double)KSEL) - tot / ((double)BN * (double)HWSZ);
    __syncthreads();
    if (c == 0) {
        int chosen[3];
        for (int j = 0; j < 3; ++j) {
            double bv = -1e300; int bi = 0;
            for (int i = 0; i < CCH; ++i) {
                bool skip = false;
                for (int jj = 0; jj < j; ++jj) if (chosen[jj] == i) skip = true;
                if (!skip && delta[i] > bv) { bv = delta[i]; bi = i; }  // strict >: lower idx wins ties
            }
            chosen[j] = bi;
            out[j] = bi;
        }
    }
}

extern "C" void kernel_launch(void* const* d_in, const int* in_sizes, int n_in,
                              void* d_out, int out_size, void* d_ws, size_t ws_size,
                              hipStream_t stream) {
    const float* hsi = (const float*)d_in[0];
    const float* w   = (const float*)d_in[1];
    int* out = (int*)d_out;

    char* ws = (char*)d_ws;
    double*   total_sum = (double*)(ws);               // 4 KB
    double*   topk_sum  = (double*)(ws + 4096);        // 4 KB
    unsigned* hist_ws   = (unsigned*)(ws + (1 << 20)); // 2048*1024*4 = 8 MB

    hipLaunchKernelGGL(hist_kernel,   dim3(NB1), dim3(NT1), 0, stream, hsi, hist_ws);
    hipLaunchKernelGGL(reduce_kernel, dim3(NG),  dim3(NT2), 0, stream, hist_ws, w, total_sum, topk_sum);
    hipLaunchKernelGGL(final_kernel,  dim3(1),   dim3(CCH), 0, stream, total_sum, topk_sum, out);
}